// Round 8
// baseline (409.156 us; speedup 1.0000x reference)
//
#include <hip/hip_runtime.h>
#include <math.h>

#define BB 2
#define TT 2048
#define DD 1024
#define HH 16
#define INNERD 512
#define FFD 4096
#define NPROJ 2560     // D + 3*INNER
#define CATD 3072      // 3*D
#define MROWS (BB*TT)  // 4096
#define CHUNK 64
#define NCH (TT/CHUNK) // 32
#define BH 32          // B*H

typedef __bf16 bf16;
typedef __attribute__((ext_vector_type(8))) __bf16 bf16x8;
typedef __attribute__((ext_vector_type(4))) __bf16 bf16x4;
typedef __attribute__((ext_vector_type(4))) float f32x4;

struct Part4 { void* p0; void* p1; void* p2; void* p3; };

// ---------------------------------------------------------------- fused prep:
// blocks [0,4096): LN1 row kernel
// blocks [4096,18432): 32x32 transpose tiles for the 5 weights
__global__ __launch_bounds__(256) void prep_fused(
    const float* __restrict__ inputs, const float* __restrict__ ln1_g,
    const float* __restrict__ ln1_b, bf16* __restrict__ normed,
    const float* __restrict__ W_in,  bf16* __restrict__ wt_in,
    const float* __restrict__ W_c,   bf16* __restrict__ wt_c,
    const float* __restrict__ W_mix, bf16* __restrict__ wt_mix,
    const float* __restrict__ W1,    bf16* __restrict__ wt1,
    const float* __restrict__ W2,    bf16* __restrict__ wt2)
{
    int blk = blockIdx.x, tid = threadIdx.x;
    if (blk < MROWS) {
        // ---- LN1 ----
        int row = blk;
        f32x4 xv = ((const f32x4*)(inputs + (size_t)row * DD))[tid];
        float s = xv[0] + xv[1] + xv[2] + xv[3];
        float s2 = xv[0]*xv[0] + xv[1]*xv[1] + xv[2]*xv[2] + xv[3]*xv[3];
        #pragma unroll
        for (int off = 32; off > 0; off >>= 1) {
            s  += __shfl_xor(s,  off, 64);
            s2 += __shfl_xor(s2, off, 64);
        }
        __shared__ float rs[4], rs2[4];
        int wid = tid >> 6;
        if ((tid & 63) == 0) { rs[wid] = s; rs2[wid] = s2; }
        __syncthreads();
        s  = rs[0] + rs[1] + rs[2] + rs[3];
        s2 = rs2[0] + rs2[1] + rs2[2] + rs2[3];
        float mean = s * (1.0f / DD);
        float var  = s2 * (1.0f / DD) - mean * mean;
        float rstd = rsqrtf(var + 1e-5f);
        f32x4 gv = ((const f32x4*)ln1_g)[tid];
        f32x4 bv = ((const f32x4*)ln1_b)[tid];
        bf16x4 o;
        #pragma unroll
        for (int q = 0; q < 4; q++)
            o[q] = (bf16)((xv[q] - mean) * rstd * gv[q] + bv[q]);
        ((bf16x4*)(normed + (size_t)row * DD))[tid] = o;
        return;
    }
    // ---- transpose fp32(K,N) -> bf16(N,K), 32x32 tiles ----
    int tb = blk - MROWS;
    const float* W; bf16* Wt; int Kd, Nd;
    if      (tb < 2560)  {             W = W_in;  Wt = wt_in;  Kd = 1024; Nd = 2560; }
    else if (tb < 3072)  { tb -= 2560; W = W_c;   Wt = wt_c;   Kd = 512;  Nd = 1024; }
    else if (tb < 6144)  { tb -= 3072; W = W_mix; Wt = wt_mix; Kd = 3072; Nd = 1024; }
    else if (tb < 10240) { tb -= 6144; W = W1;    Wt = wt1;    Kd = 1024; Nd = 4096; }
    else                 { tb -= 10240;W = W2;    Wt = wt2;    Kd = 4096; Nd = 1024; }
    int ntx = Nd >> 5;
    int nb = (tb % ntx) * 32, kb = (tb / ntx) * 32;
    __shared__ float t[32][33];
    int tx = tid & 31, ty = tid >> 5;   // 32 x 8
    #pragma unroll
    for (int r = 0; r < 32; r += 8)
        t[ty + r][tx] = W[(size_t)(kb + ty + r) * Nd + nb + tx];
    __syncthreads();
    #pragma unroll
    for (int r = 0; r < 32; r += 8)
        Wt[(size_t)(nb + ty + r) * Kd + kb + tx] = (bf16)t[tx][ty + r];
}

// ---------------------------------------------------------------- MFMA GEMM, BK=64, 4 blocks/CU
// Grid is (M/128, N/128, z) — m from blockIdx.x so same-A blocks (which
// differ only in n) land on the SAME XCD (linear%8 == bx%8).
// EPI 0: +bias -> bf16 Cb      EPI 1: fast-gelu(+bias) -> bf16 Cb
// EPI 4: bf16 partial -> part.p[z] (ldc=DD)
template<int EPI>
__global__ __launch_bounds__(256, 4) void gemm_mfma(
    const bf16* __restrict__ A,  int lda,
    const bf16* __restrict__ Bt, int ldb,
    const float* __restrict__ bias,
    bf16* __restrict__ Cb, int ldc,
    int K, Part4 part)
{
    __shared__ bf16 As[128 * 64];   // chunk-contiguous: 16 chunks of 16rows x 32k
    __shared__ bf16 Bs[128 * 64];
    const int tid  = threadIdx.x;
    const int wave = tid >> 6, lane = tid & 63;
    const int m0 = blockIdx.x * 128, n0 = blockIdx.y * 128;   // grid-transposed
    const int koff = blockIdx.z * K;
    A  += koff;
    Bt += koff;
    const int wr = wave >> 1, wc = wave & 1;
    const int lrow = lane >> 2;          // staging row within 16-row chunk
    const int lcol = (lane & 3) * 8;     // staging k offset within 32-k half
    const int fm = lane & 15;            // fragment m/n within 16-tile
    const int fk = (lane >> 4) * 8;      // fragment k offset

    f32x4 acc[4][4];
    #pragma unroll
    for (int i = 0; i < 4; i++)
        #pragma unroll
        for (int j = 0; j < 4; j++)
            acc[i][j] = (f32x4){0.f, 0.f, 0.f, 0.f};

    for (int k0 = 0; k0 < K; k0 += 64) {
        #pragma unroll
        for (int r = 0; r < 4; r++) {
            int c  = r * 4 + wave;            // chunk 0..15
            int rc = c >> 1, kh = c & 1;      // row-chunk, k-half
            const bf16* ga = A  + (size_t)(m0 + rc * 16 + lrow) * lda + k0 + kh * 32 + lcol;
            const bf16* gb = Bt + (size_t)(n0 + rc * 16 + lrow) * ldb + k0 + kh * 32 + lcol;
            __builtin_amdgcn_global_load_lds(
                (const __attribute__((address_space(1))) void*)ga,
                (__attribute__((address_space(3))) void*)(As + c * 512), 16, 0, 0);
            __builtin_amdgcn_global_load_lds(
                (const __attribute__((address_space(1))) void*)gb,
                (__attribute__((address_space(3))) void*)(Bs + c * 512), 16, 0, 0);
        }
        __syncthreads();
        #pragma unroll
        for (int ks = 0; ks < 2; ks++) {
            bf16x8 af[4], bfv[4];
            #pragma unroll
            for (int i = 0; i < 4; i++)
                af[i] = *(const bf16x8*)(As + (wr * 4 + i) * 1024 + ks * 512 + fm * 32 + fk);
            #pragma unroll
            for (int j = 0; j < 4; j++)
                bfv[j] = *(const bf16x8*)(Bs + (wc * 4 + j) * 1024 + ks * 512 + fm * 32 + fk);
            #pragma unroll
            for (int i = 0; i < 4; i++)
                #pragma unroll
                for (int j = 0; j < 4; j++)
                    acc[i][j] = __builtin_amdgcn_mfma_f32_16x16x32_bf16(
                        af[i], bfv[j], acc[i][j], 0, 0, 0);
        }
        __syncthreads();
    }

    void* psel = nullptr;
    if constexpr (EPI == 4) {
        int z = blockIdx.z;
        psel = (z == 0) ? part.p0 : (z == 1) ? part.p1 : (z == 2) ? part.p2 : part.p3;
    }

    #pragma unroll
    for (int i = 0; i < 4; i++) {
        int mbase = m0 + wr * 64 + i * 16 + (lane >> 4) * 4;
        #pragma unroll
        for (int j = 0; j < 4; j++) {
            int col = n0 + wc * 64 + j * 16 + (lane & 15);
            float bv = 0.f;
            if constexpr (EPI == 0 || EPI == 1) bv = bias[col];
            #pragma unroll
            for (int r = 0; r < 4; r++) {
                int row = mbase + r;
                float v = acc[i][j][r] + bv;
                if constexpr (EPI == 0) {
                    Cb[(size_t)row * ldc + col] = (bf16)v;
                } else if constexpr (EPI == 1) {
                    // fast gelu: x * sigmoid(1.5957691x + 0.07135502x^3)
                    float z2 = v * (1.5957691f + 0.07135502f * v * v);
                    v = v / (1.0f + __expf(-z2));
                    Cb[(size_t)row * ldc + col] = (bf16)v;
                } else {
                    ((bf16*)psel)[(size_t)row * DD + col] = (bf16)v;
                }
            }
        }
    }
}

// ---------------------------------------------------------------- fused epilogue: W_mix (3 bf16 partials) gate + residual + mask, then LN2
__global__ __launch_bounds__(256) void epi_mix_ln2(
    const bf16* __restrict__ P0, const bf16* __restrict__ P1,
    const bf16* __restrict__ P2, const float* __restrict__ bias,
    const bf16* __restrict__ proj, const float* __restrict__ res,
    const float* __restrict__ mask,
    const float* __restrict__ g2, const float* __restrict__ b2v,
    float* __restrict__ out1, bf16* __restrict__ hbuf)
{
    int row = blockIdx.x, tid = threadIdx.x;
    float m = mask[row];
    size_t off = (size_t)row * DD + tid * 4;
    bf16x4 s0 = *(const bf16x4*)(P0 + off);
    bf16x4 s1 = *(const bf16x4*)(P1 + off);
    bf16x4 s2v = *(const bf16x4*)(P2 + off);
    f32x4 bv = ((const f32x4*)bias)[tid];
    bf16x4 g4 = *(const bf16x4*)(proj + (size_t)row * NPROJ + tid * 4);
    f32x4 rv = ((const f32x4*)(res + (size_t)row * DD))[tid];
    f32x4 v;
    #pragma unroll
    for (int q = 0; q < 4; q++) {
        float sg = 1.0f / (1.0f + __expf(-(float)g4[q]));
        float sv = (float)s0[q] + (float)s1[q] + (float)s2v[q] + bv[q];
        v[q] = (rv[q] + sg * sv) * m;
    }
    ((f32x4*)(out1 + (size_t)row * DD))[tid] = v;
    // LN2
    float s = v[0] + v[1] + v[2] + v[3];
    float s2 = v[0]*v[0] + v[1]*v[1] + v[2]*v[2] + v[3]*v[3];
    #pragma unroll
    for (int off2 = 32; off2 > 0; off2 >>= 1) {
        s  += __shfl_xor(s,  off2, 64);
        s2 += __shfl_xor(s2, off2, 64);
    }
    __shared__ float rs[4], rs2[4];
    int wid = tid >> 6;
    if ((tid & 63) == 0) { rs[wid] = s; rs2[wid] = s2; }
    __syncthreads();
    s  = rs[0] + rs[1] + rs[2] + rs[3];
    s2 = rs2[0] + rs2[1] + rs2[2] + rs2[3];
    float mean = s * (1.0f / DD);
    float var  = s2 * (1.0f / DD) - mean * mean;
    float rstd = rsqrtf(var + 1e-5f);
    f32x4 gg = ((const f32x4*)g2)[tid];
    f32x4 bb = ((const f32x4*)b2v)[tid];
    bf16x4 h;
    #pragma unroll
    for (int q = 0; q < 4; q++)
        h[q] = (bf16)((v[q] - mean) * rstd * gg[q] + bb[q]);
    ((bf16x4*)(hbuf + (size_t)row * DD))[tid] = h;
}

// ---------------------------------------------------------------- final epilogue: out = (out1 + sum 4 bf16 partials + b2) * mask
__global__ __launch_bounds__(256) void epi_w2(
    float* __restrict__ d_out, const float* __restrict__ out1,
    const bf16* __restrict__ P0, const bf16* __restrict__ P1,
    const bf16* __restrict__ P2, const bf16* __restrict__ P3,
    const float* __restrict__ bias, const float* __restrict__ mask)
{
    int id = blockIdx.x * 256 + threadIdx.x;    // over MROWS*DD/4
    int row = id >> 8;                          // 256 f32x4 per row
    float m = mask[row];
    bf16x4 a0 = ((const bf16x4*)P0)[id];
    bf16x4 a1 = ((const bf16x4*)P1)[id];
    bf16x4 a2 = ((const bf16x4*)P2)[id];
    bf16x4 a3 = ((const bf16x4*)P3)[id];
    f32x4 r = ((const f32x4*)out1)[id];
    f32x4 b = ((const f32x4*)bias)[id & 255];
    f32x4 o;
    #pragma unroll
    for (int q = 0; q < 4; q++) {
        float sv = (float)a0[q] + (float)a1[q] + (float)a2[q] + (float)a3[q];
        o[q] = (r[q] + sv + b[q]) * m;
    }
    ((f32x4*)d_out)[id] = o;
}

// ---------------------------------------------------------------- attention helpers
__device__ __forceinline__ float phi_f(float x) {
    return x > 0.f ? x + 1.f : __expf(x);   // elu(x)+1
}

// ---------------------------------------------------------------- mid fused:
// blocks [0,1024): dwconv (both kernels, 2 rows/thread, vectorized)
// blocks [1024,1536): attn phase A local sums — waves 0,1 each own one chunk
__global__ __launch_bounds__(256) void mid_fused(
    const bf16* __restrict__ x,
    const float* __restrict__ w_t, const float* __restrict__ b_t,
    const float* __restrict__ w_p, const float* __restrict__ b_p,
    bf16* __restrict__ cat,
    const bf16* __restrict__ proj, const float* __restrict__ mask,
    float* __restrict__ kvsum, float* __restrict__ kssum)
{
    __shared__ float s_ks[2][CHUNK][32], s_vs[2][CHUNK][32];   // 32 KB
    int blk = blockIdx.x, tid = threadIdx.x;
    if (blk < 1024) {
        // ---- dwconv ----
        int id = blk * 256 + tid;                // over (MROWS/2)*128
        int cg = id & 127, rp = id >> 7;
        int c0 = cg * 8;
        int row0 = rp * 2;
        int t0 = row0 & (TT - 1);
        bf16x8 xw[16];
        #pragma unroll
        for (int j = 0; j < 16; j++) {
            int t = t0 - 14 + j;
            if (t >= 0)
                xw[j] = *(const bf16x8*)(x + (size_t)(row0 - 14 + j) * DD + c0);
            else
                #pragma unroll
                for (int q = 0; q < 8; q++) xw[j][q] = (bf16)0.f;
        }
        float y15[2][8], y3[2][8];
        #pragma unroll
        for (int q = 0; q < 8; q++) {
            float bp = b_p[c0 + q], bt = b_t[c0 + q];
            y15[0][q] = bp; y15[1][q] = bp;
            y3[0][q] = bt;  y3[1][q] = bt;
        }
        #pragma unroll
        for (int i = 0; i < 15; i++) {
            float wp[8];
            #pragma unroll
            for (int q = 0; q < 8; q++) wp[q] = w_p[(c0 + q) * 15 + i];
            #pragma unroll
            for (int rr = 0; rr < 2; rr++)
                #pragma unroll
                for (int q = 0; q < 8; q++)
                    y15[rr][q] = fmaf(wp[q], (float)xw[rr + i][q], y15[rr][q]);
        }
        #pragma unroll
        for (int i = 0; i < 3; i++) {
            float wt[8];
            #pragma unroll
            for (int q = 0; q < 8; q++) wt[q] = w_t[(c0 + q) * 3 + i];
            #pragma unroll
            for (int rr = 0; rr < 2; rr++)
                #pragma unroll
                for (int q = 0; q < 8; q++)
                    y3[rr][q] = fmaf(wt[q], (float)xw[rr + 12 + i][q], y3[rr][q]);
        }
        #pragma unroll
        for (int rr = 0; rr < 2; rr++) {
            bf16x8 o3, o15;
            #pragma unroll
            for (int q = 0; q < 8; q++) { o3[q] = (bf16)y3[rr][q]; o15[q] = (bf16)y15[rr][q]; }
            *(bf16x8*)(cat + (size_t)(row0 + rr) * CATD + DD + c0)     = o3;
            *(bf16x8*)(cat + (size_t)(row0 + rr) * CATD + 2 * DD + c0) = o15;
        }
        return;
    }
    // ---- attn phase A ----
    int w = tid >> 6;
    if (w >= 2) return;
    int lane = tid & 63;
    int ci = (blk - 1024) * 2 + w;     // chunk id 0..1023 == bh*NCH + c
    int c  = ci & (NCH - 1);
    int bh = ci >> 5;
    int b  = bh >> 4, hh = bh & (HH - 1);
    float (*ks)[32] = s_ks[w];
    float (*vs)[32] = s_vs[w];
    int row0 = b * TT + c * CHUNK;
    {
        int row = row0 + lane;
        float m = mask[row];
        const bf16* kp = proj + (size_t)row * NPROJ + DD + INNERD + hh * 32;
        const bf16* vp = kp + INNERD;
        #pragma unroll
        for (int s = 0; s < 4; s++) {
            bf16x8 k8 = *(const bf16x8*)(kp + s * 8);
            bf16x8 v8 = *(const bf16x8*)(vp + s * 8);
            #pragma unroll
            for (int q = 0; q < 8; q++) {
                ks[lane][s * 8 + q] = phi_f((float)k8[q]) * m;
                vs[lane][s * 8 + q] = (float)v8[q] * m;
            }
        }
    }
    // wave-synchronous: same wave wrote, same wave reads
    int e = lane & 31, d0 = (lane >> 5) * 16;
    float kv[16], ksl[16];
    #pragma unroll
    for (int j = 0; j < 16; j++) { kv[j] = 0.f; ksl[j] = 0.f; }
    for (int t = 0; t < CHUNK; t++) {
        float ve = vs[t][e];
        f32x4 kr[4];
        #pragma unroll
        for (int s = 0; s < 4; s++) kr[s] = *(const f32x4*)&ks[t][d0 + s * 4];
        #pragma unroll
        for (int j = 0; j < 16; j++) {
            float kval = kr[j >> 2][j & 3];
            kv[j] = fmaf(kval, ve, kv[j]);
            ksl[j] += kval;
        }
    }
    size_t base = (size_t)ci * 1024;
    #pragma unroll
    for (int j = 0; j < 16; j++)
        kvsum[base + (size_t)(d0 + j) * 32 + e] = kv[j];
    if (e == 0) {
        #pragma unroll
        for (int j = 0; j < 16; j++)
            kssum[ci * 32 + d0 + j] = ksl[j];
    }
}

// Phase C: in-chunk scan, LDS-resident, with INLINE exclusive prefix over
// earlier chunks' kvsum/kssum (removes the attn_prefix dispatch).
__global__ __launch_bounds__(64) void attn_scan(
    const bf16* __restrict__ proj, const float* __restrict__ mask,
    const float* __restrict__ kvsum, const float* __restrict__ kssum,
    bf16* __restrict__ attn_out)
{
    int blk = blockIdx.x;
    int c  = blk & (NCH - 1);
    int bh = blk >> 5;
    int b  = bh >> 4, hh = bh & (HH - 1);
    int lane = threadIdx.x;
    __shared__ float qs[CHUNK][32], ks[CHUNK][32], vs[CHUNK][32];
    __shared__ float ms[CHUNK];
    int row0 = b * TT + c * CHUNK;
    {
        int row = row0 + lane;
        float m = mask[row];
        ms[lane] = m;
        const bf16* qp = proj + (size_t)row * NPROJ + DD + hh * 32;
        const bf16* kp = qp + INNERD;
        const bf16* vp = kp + INNERD;
        #pragma unroll
        for (int s = 0; s < 4; s++) {
            bf16x8 q8 = *(const bf16x8*)(qp + s * 8);
            bf16x8 k8 = *(const bf16x8*)(kp + s * 8);
            bf16x8 v8 = *(const bf16x8*)(vp + s * 8);
            #pragma unroll
            for (int q = 0; q < 8; q++) {
                qs[lane][s * 8 + q] = phi_f((float)q8[q]) * m;
                ks[lane][s * 8 + q] = phi_f((float)k8[q]) * m;
                vs[lane][s * 8 + q] = (float)v8[q] * m;
            }
        }
    }
    int e = lane & 31, d0 = (lane >> 5) * 16;
    float kv[16], ksl[16];
    #pragma unroll
    for (int j = 0; j < 16; j++) { kv[j] = 0.f; ksl[j] = 0.f; }
    // inline exclusive prefix: sum earlier chunks' local sums
    for (int cp = 0; cp < c; cp++) {
        size_t cb = (size_t)(bh * NCH + cp) * 1024;
        #pragma unroll
        for (int j = 0; j < 16; j++)
            kv[j] += kvsum[cb + (size_t)(d0 + j) * 32 + e];
        #pragma unroll
        for (int j = 0; j < 16; j++)
            ksl[j] += kssum[(bh * NCH + cp) * 32 + d0 + j];
    }
    __syncthreads();
    for (int t = 0; t < CHUNK; t++) {
        float ve = vs[t][e];
        f32x4 kr[4], qr[4];
        #pragma unroll
        for (int s = 0; s < 4; s++) kr[s] = *(const f32x4*)&ks[t][d0 + s * 4];
        #pragma unroll
        for (int s = 0; s < 4; s++) qr[s] = *(const f32x4*)&qs[t][d0 + s * 4];
        float num0 = 0.f, num1 = 0.f, den0 = 0.f, den1 = 0.f;
        #pragma unroll
        for (int j = 0; j < 16; j++) {
            float kval = kr[j >> 2][j & 3], qval = qr[j >> 2][j & 3];
            kv[j]  = fmaf(kval, ve, kv[j]);   // inclusive cumsum
            ksl[j] += kval;
            if (j & 1) { num1 = fmaf(qval, kv[j], num1); den1 = fmaf(qval, ksl[j], den1); }
            else       { num0 = fmaf(qval, kv[j], num0); den0 = fmaf(qval, ksl[j], den0); }
        }
        float num = num0 + num1, den = den0 + den1;
        num += __shfl_xor(num, 32, 64);
        den += __shfl_xor(den, 32, 64);
        if (lane < 32)
            attn_out[(size_t)(row0 + t) * INNERD + hh * 32 + e] =
                (bf16)(num / (den + 1e-6f) * ms[t]);
    }
}

// ---------------------------------------------------------------- launch
extern "C" void kernel_launch(void* const* d_in, const int* in_sizes, int n_in,
                              void* d_out, int out_size, void* d_ws, size_t ws_size,
                              hipStream_t stream)
{
    const float* inputs = (const float*)d_in[0];
    const float* mask   = (const float*)d_in[1];
    const float* ln1_g  = (const float*)d_in[2];
    const float* ln1_b  = (const float*)d_in[3];
    const float* W_in   = (const float*)d_in[4];
    const float* b_in   = (const float*)d_in[5];
    const float* W_c    = (const float*)d_in[6];
    const float* b_c    = (const float*)d_in[7];
    const float* w_t    = (const float*)d_in[8];
    const float* b_t    = (const float*)d_in[9];
    const float* w_p    = (const float*)d_in[10];
    const float* b_p    = (const float*)d_in[11];
    const float* W_mix  = (const float*)d_in[12];
    const float* b_mix  = (const float*)d_in[13];
    const float* ln2_g  = (const float*)d_in[14];
    const float* ln2_b  = (const float*)d_in[15];
    const float* W1     = (const float*)d_in[16];
    const float* b1     = (const float*)d_in[17];
    const float* W2     = (const float*)d_in[18];
    const float* b2     = (const float*)d_in[19];
    float* out = (float*)d_out;

    // workspace layout (bytes). ffn1 aliases [normed|proj|attnb] (dead by W1).
    // attn kv scratch aliases out1 (dead until epi_mix_ln2).
    // Split-K bf16 partials (non-atomic, fully overwritten by their GEMM):
    //   W_mix: d_out (2 partials), hbuf-region
    //   W2  : cat-region (3 partials), hbuf-region
    char* p = (char*)d_ws;
    bf16* normed = (bf16*)p;  p += (size_t)MROWS * DD * 2;
    bf16* proj   = (bf16*)p;  p += (size_t)MROWS * NPROJ * 2;
    bf16* attnb  = (bf16*)p;  p += (size_t)MROWS * INNERD * 2;
    bf16* cat    = (bf16*)p;  p += (size_t)MROWS * CATD * 2;
    float* out1  = (float*)p; p += (size_t)MROWS * DD * 4;
    bf16* hbuf   = (bf16*)p;  p += (size_t)MROWS * DD * 2;
    bf16* wt_in  = (bf16*)p;  p += (size_t)NPROJ * DD * 2;
    bf16* wt_c   = (bf16*)p;  p += (size_t)DD * INNERD * 2;
    bf16* wt_mix = (bf16*)p;  p += (size_t)DD * CATD * 2;
    bf16* wt1    = (bf16*)p;  p += (size_t)FFD * DD * 2;
    bf16* wt2    = (bf16*)p;  p += (size_t)DD * FFD * 2;
    bf16* ffn1   = (bf16*)d_ws;                  // alias [normed|proj|attnb]
    float* kvsum = out1;                         // alias out1 region (attn)
    float* kssum = kvsum + (size_t)BH * NCH * 1024;
    // split-K bf16 partials
    bf16*  m_p0  = (bf16*)d_out;
    bf16*  m_p1  = (bf16*)d_out + (size_t)MROWS * DD;
    bf16*  m_p2  = hbuf;
    bf16*  w2_p0 = cat;
    bf16*  w2_p1 = cat + (size_t)MROWS * DD;
    bf16*  w2_p2 = cat + (size_t)MROWS * DD * 2;
    bf16*  w2_p3 = hbuf;

    // 1. fused prep: LN1 + all 5 weight transposes (one dispatch)
    prep_fused<<<MROWS + 14336, 256, 0, stream>>>(
        inputs, ln1_g, ln1_b, normed,
        W_in, wt_in, W_c, wt_c, W_mix, wt_mix, W1, wt1, W2, wt2);
    // 2. proj = normed @ W_in + b_in (bf16 out)   grid (M,N)
    gemm_mfma<0><<<dim3(MROWS/128, NPROJ/128), 256, 0, stream>>>(
        normed, DD, wt_in, DD, b_in, proj, NPROJ, DD, Part4{});
    // 3. fused dwconv + attn phase A (one dispatch)
    mid_fused<<<1024 + 512, 256, 0, stream>>>(
        normed, w_t, b_t, w_p, b_p, cat, proj, mask, kvsum, kssum);
    // 4. attn scan with inline prefix -> attnb
    attn_scan<<<BH * NCH, 64, 0, stream>>>(proj, mask, kvsum, kssum, attnb);
    // 5. cat[:,0:D] = attnb @ W_c + b_c  (direct, no split: K=512 is short)
    gemm_mfma<0><<<dim3(MROWS/128, DD/128), 256, 0, stream>>>(
        attnb, INNERD, wt_c, INNERD, b_c, cat, CATD, INNERD, Part4{});
    // 6. W_mix split-3 bf16 partials
    gemm_mfma<4><<<dim3(MROWS/128, DD/128, 3), 256, 0, stream>>>(
        cat, CATD, wt_mix, CATD, nullptr, nullptr, DD, CATD / 3,
        Part4{m_p0, m_p1, m_p2, nullptr});
    // 7. out1 = (inputs + sigmoid(gate)*(sum P + b_mix))*mask ; hbuf = LN2(out1)
    epi_mix_ln2<<<MROWS, 256, 0, stream>>>(m_p0, m_p1, m_p2, b_mix, proj, inputs,
                                           mask, ln2_g, ln2_b, out1, hbuf);
    // 8. ffn1 = gelu(hbuf @ W1 + b1) (bf16 out; aliases dead normed/proj/attnb)
    gemm_mfma<1><<<dim3(MROWS/128, FFD/128), 256, 0, stream>>>(
        hbuf, DD, wt1, DD, b1, ffn1, FFD, DD, Part4{});
    // 9. W2 split-4 bf16 partials
    gemm_mfma<4><<<dim3(MROWS/128, DD/128, 4), 256, 0, stream>>>(
        ffn1, FFD, wt2, FFD, nullptr, nullptr, DD, FFD / 4,
        Part4{w2_p0, w2_p1, w2_p2, w2_p3});
    // 10. out = (out1 + sum P + b2) * mask
    epi_w2<<<MROWS * DD / 4 / 256, 256, 0, stream>>>(out, out1, w2_p0, w2_p1,
                                                     w2_p2, w2_p3, b2, mask);
}